// Round 4
// baseline (75.677 us; speedup 1.0000x reference)
//
#include <hip/hip_runtime.h>

#define NA 3
#define NCLS 3
#define NB 12
#define BATCH 128
#define UNITS 1792

// Anchors per scale (already divided by stride)
__device__ __constant__ float AWc[3][3] = {{3.625f, 4.875f, 11.65625f},
                                           {1.875f, 3.875f, 3.6875f},
                                           {1.25f,  2.0f,   4.125f}};
__device__ __constant__ float AHc[3][3] = {{2.8125f, 6.1875f, 10.1875f},
                                           {3.8125f, 2.8125f, 7.4375f},
                                           {1.625f,  3.75f,   2.875f}};

__device__ __forceinline__ float safelog(float x) {
    return fmaxf(__logf(x), -100.0f);
}

// skey per box: bits 0..15 = rem (gj*G+gi), bits 16..22 = flags, bits 24..25 = cls
// flags: bits 0..2 = clear mask per anchor (ANDed with valid)
//        bits 4..6 = obj mask (valid ? 1<<best : 0)

template <int G, int S>
__device__ __forceinline__ float cell_loss(int c, const float* __restrict__ outb,
                                           const int* rk, const float* sdat) {
    constexpr int GG = G * G;
    const float* cp = outb + (size_t)c * 8;
    float4 q0 = *(const float4*)cp;
    float4 q1 = *(const float4*)(cp + 4);

    int a   = c / GG;                 // const divide -> magic mul
    int rem = c - a * GG;

    float keepv = 1.0f;
    int objn = -1;
#pragma unroll
    for (int n = 0; n < NB; n++) {
        int pk = rk[n];
        bool hit = ((pk & 0xFFFF) == rem);
        int fl = pk >> 16;
        if (hit && ((fl >> a) & 1)) keepv = 0.0f;       // -> v_cndmask
        if (hit && ((fl >> (4 + a)) & 1)) objn = n;     // -> v_cndmask
    }

    float conf = q1.x;
    float loss = -0.5f * keepv * safelog(1.0f - conf);  // NOOBJ_SCALE*bce(conf,0)

    if (objn >= 0) {                 // rare (<=12 cells per image-scale), no loads inside
        int pk = rk[objn];
        int cls = (pk >> 24) & 3;
        float tw = sdat[objn], th = sdat[NB + objn];
        float aws = AWc[S][a], ahs = AHc[S][a];
        float px = q0.x - floorf(q0.x);
        float py = q0.y - floorf(q0.y);
        float pw = __logf(q0.z / aws + 1e-16f);
        float ph = __logf(q0.w / ahs + 1e-16f);
        float dw = pw - tw, dh = ph - th;
        loss += px * px + py * py + dw * dw + dh * dh;
        loss += -5.0f * safelog(conf);                  // OBJ_SCALE*bce(conf,1)
        float c0 = q1.y, c1 = q1.z, c2 = q1.w;
        loss -= (cls == 0) ? safelog(c0) : safelog(1.0f - c0);
        loss -= (cls == 1) ? safelog(c1) : safelog(1.0f - c1);
        loss -= (cls == 2) ? safelog(c2) : safelog(1.0f - c2);
    }
    return loss;
}

template <int G, int S, int ITER>
__device__ __forceinline__ float scale_body(int b, int chunk,
        const float* __restrict__ outp,
        const float* __restrict__ boxes,
        const int* __restrict__ labels,
        int* skey, float* sdat)
{
    constexpr int GG = G * G;
    constexpr int CELLS = NA * GG;
    const int tid = threadIdx.x;

    // ---- in-block box meta (threads 0..11) ----
    if (tid < NB) {
        float4 bx = ((const float4*)boxes)[b * NB + tid];
        int lab = labels[b * NB + tid];
        bool valid = lab < NCLS;

        float bw = bx.z * (float)G, bh = bx.w * (float)G;
        int gi = min(max((int)(bx.x * (float)G), 0), G - 1);
        int gj = min(max((int)(bx.y * (float)G), 0), G - 1);

        float iou[3]; int best = 0; float bi = -1.0f;
#pragma unroll
        for (int a = 0; a < 3; a++) {
            float aw = AWc[S][a], ah = AHc[S][a];
            float inter = fminf(aw, bw) * fminf(ah, bh);
            float uni = aw * ah + 1e-16f + bw * bh - inter;
            iou[a] = inter / uni;
            if (iou[a] > bi) { bi = iou[a]; best = a; }
        }
        int flags = 0;
        if (valid) {
#pragma unroll
            for (int a = 0; a < 3; a++)
                if (iou[a] > 0.5f || a == best) flags |= (1 << a);
            flags |= (1 << (4 + best));
        }
        int cls = min(max(lab, 0), NCLS - 1);
        skey[tid] = (gj * G + gi) | (flags << 16) | (cls << 24);
        sdat[tid]      = valid ? __logf(bw / AWc[S][best] + 1e-16f) : 0.0f;
        sdat[NB + tid] = valid ? __logf(bh / AHc[S][best] + 1e-16f) : 0.0f;
    }
    __syncthreads();

    // box keys -> SGPRs (block-uniform)
    int rk[NB];
#pragma unroll
    for (int n = 0; n < NB; n++) rk[n] = __builtin_amdgcn_readfirstlane(skey[n]);

    const float* outb = outp + (size_t)b * CELLS * 8;
    float acc = 0.0f;
    const int base = chunk * (256 * ITER);

    if (base + 256 * ITER <= CELLS) {
        // fast path: no bounds checks -> compiler batches all ITER load pairs
#pragma unroll
        for (int k = 0; k < ITER; k++)
            acc += cell_loss<G, S>(base + k * 256 + tid, outb, rk, sdat);
    } else {
#pragma unroll
        for (int k = 0; k < ITER; k++) {
            int c = base + k * 256 + tid;
            if (c < CELLS)
                acc += cell_loss<G, S>(c, outb, rk, sdat);
        }
    }
    return acc;
}

__launch_bounds__(256)
__global__ void fused_loss(const float* __restrict__ oL,
                           const float* __restrict__ oM,
                           const float* __restrict__ oS,
                           const float* __restrict__ boxes,
                           const int* __restrict__ labels,
                           float* __restrict__ partials,
                           unsigned int* __restrict__ counter,
                           float* __restrict__ out)
{
    __shared__ int skey[NB];
    __shared__ float sdat[2 * NB];
    __shared__ float red[256];
    __shared__ int isLast;

    const int u = blockIdx.x;
    const int tid = threadIdx.x;

    float acc;
    if (u < 128) {
        acc = scale_body<19, 0, 5>(u, 0, oL, boxes, labels, skey, sdat);
    } else if (u < 640) {
        int r = u - 128;
        acc = scale_body<38, 1, 5>(r >> 2, r & 3, oM, boxes, labels, skey, sdat);
    } else {
        int r = u - 640;
        acc = scale_body<76, 2, 8>(r / 9, r % 9, oS, boxes, labels, skey, sdat);
    }

    red[tid] = acc;
    __syncthreads();
#pragma unroll
    for (int s = 128; s > 0; s >>= 1) {
        if (tid < s) red[tid] += red[tid + s];
        __syncthreads();
    }

    if (tid == 0) {
        partials[u] = red[0];
        __threadfence();
        isLast = (atomicAdd(counter, 1u) == UNITS - 1);
    }
    __syncthreads();

    if (isLast) {   // fixed-order final sum -> bit-identical regardless of which block is last
        __threadfence();
        float a2 = 0.0f;
#pragma unroll
        for (int i = 0; i < 7; i++) a2 += partials[tid + i * 256];
        red[tid] = a2;
        __syncthreads();
#pragma unroll
        for (int s = 128; s > 0; s >>= 1) {
            if (tid < s) red[tid] += red[tid + s];
            __syncthreads();
        }
        if (tid == 0) out[0] = red[0] * (1.0f / (float)BATCH);
    }
}

extern "C" void kernel_launch(void* const* d_in, const int* in_sizes, int n_in,
                              void* d_out, int out_size, void* d_ws, size_t ws_size,
                              hipStream_t stream) {
    const float* oL     = (const float*)d_in[0];
    const float* oM     = (const float*)d_in[1];
    const float* oS     = (const float*)d_in[2];
    const float* boxes  = (const float*)d_in[3];
    const int*   labels = (const int*)d_in[4];

    float* partials   = (float*)d_ws;                         // UNITS floats
    unsigned* counter = (unsigned*)((char*)d_ws + UNITS * sizeof(float));

    hipMemsetAsync(counter, 0, sizeof(unsigned), stream);     // replay-safe counter reset
    fused_loss<<<UNITS, 256, 0, stream>>>(oL, oM, oS, boxes, labels,
                                          partials, counter, (float*)d_out);
}

// Round 7
// 43.027 us; speedup vs baseline: 1.7588x; 1.7588x over previous
//
#include <hip/hip_runtime.h>

#define NA 3
#define NCLS 3
#define NB 12
#define BATCH 128
#define UNITS 1792

// Anchors per scale (already divided by stride)
__device__ __constant__ float AWc[3][3] = {{3.625f, 4.875f, 11.65625f},
                                           {1.875f, 3.875f, 3.6875f},
                                           {1.25f,  2.0f,   4.125f}};
__device__ __constant__ float AHc[3][3] = {{2.8125f, 6.1875f, 10.1875f},
                                           {3.8125f, 2.8125f, 7.4375f},
                                           {1.625f,  3.75f,   2.875f}};

__device__ __forceinline__ float safelog(float x) {
    return fmaxf(__logf(x), -100.0f);
}

// rk per box: bits 0..15 = rem (gj*G+gi), bits 16..22 = flags, bits 24..25 = cls
// flags: bits 0..2 = clear mask per anchor (ANDed with valid)
//        bits 4..6 = obj mask (valid ? 1<<best : 0)

template <int G, int S>
__device__ __forceinline__ float cell_loss(int c, float4 q0, float4 q1,
                                           const int* rk, const float* sdat) {
    constexpr int GG = G * G;
    int a   = c / GG;                 // const divide -> magic mul
    int rem = c - a * GG;

    float keepv = 1.0f;
    int objn = -1;
#pragma unroll
    for (int n = 0; n < NB; n++) {
        int pk = rk[n];
        bool hit = ((pk & 0xFFFF) == rem);
        int fl = pk >> 16;
        if (hit && ((fl >> a) & 1)) keepv = 0.0f;       // -> v_cndmask
        if (hit && ((fl >> (4 + a)) & 1)) objn = n;     // -> v_cndmask
    }

    float conf = q1.x;
    float loss = -0.5f * keepv * safelog(1.0f - conf);  // NOOBJ_SCALE*bce(conf,0)

    if (objn >= 0) {                 // rare (<=12 cells per image-scale), no loads inside
        int pk = rk[objn];
        int cls = (pk >> 24) & 3;
        float tw = sdat[objn], th = sdat[NB + objn];
        float aws = AWc[S][a], ahs = AHc[S][a];
        float px = q0.x - floorf(q0.x);
        float py = q0.y - floorf(q0.y);
        float pw = __logf(q0.z / aws + 1e-16f);
        float ph = __logf(q0.w / ahs + 1e-16f);
        float dw = pw - tw, dh = ph - th;
        loss += px * px + py * py + dw * dw + dh * dh;
        loss += -5.0f * safelog(conf);                  // OBJ_SCALE*bce(conf,1)
        float c0 = q1.y, c1 = q1.z, c2 = q1.w;
        loss -= (cls == 0) ? safelog(c0) : safelog(1.0f - c0);
        loss -= (cls == 1) ? safelog(c1) : safelog(1.0f - c1);
        loss -= (cls == 2) ? safelog(c2) : safelog(1.0f - c2);
    }
    return loss;
}

template <int G, int S, int ITER>
__device__ __forceinline__ float scale_body(int b, int chunk,
        const float* __restrict__ outp,
        const float* __restrict__ boxes,
        const int* __restrict__ labels,
        int* skey, float* sdat)
{
    constexpr int GG = G * G;
    constexpr int CELLS = NA * GG;
    const int tid = threadIdx.x;

    // ---- in-block box meta (threads 0..11) ----
    if (tid < NB) {
        float4 bx = ((const float4*)boxes)[b * NB + tid];
        int lab = labels[b * NB + tid];
        bool valid = lab < NCLS;

        float bw = bx.z * (float)G, bh = bx.w * (float)G;
        int gi = min(max((int)(bx.x * (float)G), 0), G - 1);
        int gj = min(max((int)(bx.y * (float)G), 0), G - 1);

        float iou[3]; int best = 0; float bi = -1.0f;
#pragma unroll
        for (int a = 0; a < 3; a++) {
            float aw = AWc[S][a], ah = AHc[S][a];
            float inter = fminf(aw, bw) * fminf(ah, bh);
            float uni = aw * ah + 1e-16f + bw * bh - inter;
            iou[a] = inter / uni;
            if (iou[a] > bi) { bi = iou[a]; best = a; }
        }
        int flags = 0;
        if (valid) {
#pragma unroll
            for (int a = 0; a < 3; a++)
                if (iou[a] > 0.5f || a == best) flags |= (1 << a);
            flags |= (1 << (4 + best));
        }
        int cls = min(max(lab, 0), NCLS - 1);
        skey[tid] = (gj * G + gi) | (flags << 16) | (cls << 24);
        sdat[tid]      = valid ? __logf(bw / AWc[S][best] + 1e-16f) : 0.0f;
        sdat[NB + tid] = valid ? __logf(bh / AHc[S][best] + 1e-16f) : 0.0f;
    }
    __syncthreads();

    // box keys -> SGPRs (block-uniform)
    int rk[NB];
#pragma unroll
    for (int n = 0; n < NB; n++) rk[n] = __builtin_amdgcn_readfirstlane(skey[n]);

    const float* outb = outp + (size_t)b * CELLS * 8;
    float acc = 0.0f;
    const int base = chunk * (256 * ITER);

    // 4-wide explicit load staging: 8 dwordx4 in flight per wave; clamped
    // index keeps tail blocks branch-free (dup loads are in-bounds, masked out).
#pragma unroll
    for (int kb = 0; kb < ITER; kb += 4) {
        float4 Q0[4], Q1[4];
        int cs[4];
#pragma unroll
        for (int j = 0; j < 4; j++) {
            if (kb + j < ITER) {
                int c = base + (kb + j) * 256 + tid;
                cs[j] = c;
                int cc = (c < CELLS) ? c : (CELLS - 1);
                const float* cp = outb + (size_t)cc * 8;
                Q0[j] = *(const float4*)cp;
                Q1[j] = *(const float4*)(cp + 4);
            }
        }
#pragma unroll
        for (int j = 0; j < 4; j++) {
            if (kb + j < ITER) {
                float L = cell_loss<G, S>((cs[j] < CELLS) ? cs[j] : (CELLS - 1),
                                          Q0[j], Q1[j], rk, sdat);
                acc += (cs[j] < CELLS) ? L : 0.0f;
            }
        }
    }
    return acc;
}

__launch_bounds__(256)
__global__ void fused_loss(const float* __restrict__ oL,
                           const float* __restrict__ oM,
                           const float* __restrict__ oS,
                           const float* __restrict__ boxes,
                           const int* __restrict__ labels,
                           float* __restrict__ partials,
                           unsigned int* __restrict__ counter,
                           float* __restrict__ out)
{
    __shared__ int skey[NB];
    __shared__ float sdat[2 * NB];
    __shared__ float red[256];
    __shared__ int isLast;

    const int u = blockIdx.x;
    const int tid = threadIdx.x;

    float acc;
    if (u < 128) {
        acc = scale_body<19, 0, 5>(u, 0, oL, boxes, labels, skey, sdat);
    } else if (u < 640) {
        int r = u - 128;
        acc = scale_body<38, 1, 5>(r >> 2, r & 3, oM, boxes, labels, skey, sdat);
    } else {
        int r = u - 640;
        acc = scale_body<76, 2, 8>(r / 9, r % 9, oS, boxes, labels, skey, sdat);
    }

    red[tid] = acc;
    __syncthreads();
#pragma unroll
    for (int s = 128; s > 0; s >>= 1) {
        if (tid < s) red[tid] += red[tid + s];
        __syncthreads();
    }

    if (tid == 0) {
        // Atomic RMW executes at the DEVICE coherence point (cross-XCD safe —
        // same mechanism as the ticket counter). Returned old value kept live.
        float oldv = atomicExch(&partials[u], red[0]);
        asm volatile("" :: "v"(oldv));                      // keep RMW-with-return
        asm volatile("s_waitcnt vmcnt(0)" ::: "memory");    // exch done before ticket
        unsigned old = atomicAdd(counter, 1u);
        // counter is memset to 0 each call -> exact last-arriver test
        isLast = (old == UNITS - 1);
    }
    __syncthreads();

    if (isLast) {   // fixed-order final sum -> bit-identical regardless of which block is last
        float a2 = 0.0f;
#pragma unroll
        for (int i = 0; i < 7; i++)
            a2 += atomicAdd(&partials[tid + i * 256], 0.0f);  // RMW read at coherence point
        red[tid] = a2;
        __syncthreads();
#pragma unroll
        for (int s = 128; s > 0; s >>= 1) {
            if (tid < s) red[tid] += red[tid + s];
            __syncthreads();
        }
        if (tid == 0) out[0] = red[0] * (1.0f / (float)BATCH);
    }
}

extern "C" void kernel_launch(void* const* d_in, const int* in_sizes, int n_in,
                              void* d_out, int out_size, void* d_ws, size_t ws_size,
                              hipStream_t stream) {
    const float* oL     = (const float*)d_in[0];
    const float* oM     = (const float*)d_in[1];
    const float* oS     = (const float*)d_in[2];
    const float* boxes  = (const float*)d_in[3];
    const int*   labels = (const int*)d_in[4];

    float* partials   = (float*)d_ws;                               // UNITS floats
    unsigned* counter = (unsigned*)((char*)d_ws + UNITS * sizeof(float));

    hipMemsetAsync(counter, 0, sizeof(unsigned), stream);  // exact ticket base (graph-safe)
    fused_loss<<<UNITS, 256, 0, stream>>>(oL, oM, oS, boxes, labels,
                                          partials, counter, (float*)d_out);
}

// Round 8
// 25.547 us; speedup vs baseline: 2.9623x; 1.6842x over previous
//
#include <hip/hip_runtime.h>

#define NA 3
#define NCLS 3
#define NB 12
#define BATCH 128
#define UNITS 1792

// Anchors per scale (already divided by stride)
__device__ __constant__ float AWc[3][3] = {{3.625f, 4.875f, 11.65625f},
                                           {1.875f, 3.875f, 3.6875f},
                                           {1.25f,  2.0f,   4.125f}};
__device__ __constant__ float AHc[3][3] = {{2.8125f, 6.1875f, 10.1875f},
                                           {3.8125f, 2.8125f, 7.4375f},
                                           {1.625f,  3.75f,   2.875f}};

__device__ __forceinline__ float safelog(float x) {
    return fmaxf(__logf(x), -100.0f);
}

// rk per box: bits 0..15 = rem (gj*G+gi), bits 16..22 = flags, bits 24..25 = cls
// flags: bits 0..2 = clear mask per anchor (ANDed with valid)
//        bits 4..6 = obj mask (valid ? 1<<best : 0)

template <int G, int S>
__device__ __forceinline__ float cell_loss(int c, float4 q0, float4 q1,
                                           const int* rk, const float* sdat) {
    constexpr int GG = G * G;
    int a   = c / GG;                 // const divide -> magic mul
    int rem = c - a * GG;

    float keepv = 1.0f;
    int objn = -1;
#pragma unroll
    for (int n = 0; n < NB; n++) {
        int pk = rk[n];
        bool hit = ((pk & 0xFFFF) == rem);
        int fl = pk >> 16;
        if (hit && ((fl >> a) & 1)) keepv = 0.0f;       // -> v_cndmask
        if (hit && ((fl >> (4 + a)) & 1)) objn = n;     // -> v_cndmask
    }

    float conf = q1.x;
    float loss = -0.5f * keepv * safelog(1.0f - conf);  // NOOBJ_SCALE*bce(conf,0)

    if (objn >= 0) {                 // rare (<=12 cells per image-scale), no loads inside
        int pk = rk[objn];
        int cls = (pk >> 24) & 3;
        float tw = sdat[objn], th = sdat[NB + objn];
        float aws = AWc[S][a], ahs = AHc[S][a];
        float px = q0.x - floorf(q0.x);
        float py = q0.y - floorf(q0.y);
        float pw = __logf(q0.z / aws + 1e-16f);
        float ph = __logf(q0.w / ahs + 1e-16f);
        float dw = pw - tw, dh = ph - th;
        loss += px * px + py * py + dw * dw + dh * dh;
        loss += -5.0f * safelog(conf);                  // OBJ_SCALE*bce(conf,1)
        float c0 = q1.y, c1 = q1.z, c2 = q1.w;
        loss -= (cls == 0) ? safelog(c0) : safelog(1.0f - c0);
        loss -= (cls == 1) ? safelog(c1) : safelog(1.0f - c1);
        loss -= (cls == 2) ? safelog(c2) : safelog(1.0f - c2);
    }
    return loss;
}

template <int G, int S, int ITER>
__device__ __forceinline__ float scale_body(int b, int chunk,
        const float* __restrict__ outp,
        const float* __restrict__ boxes,
        const int* __restrict__ labels,
        int* skey, float* sdat)
{
    constexpr int GG = G * G;
    constexpr int CELLS = NA * GG;
    const int tid = threadIdx.x;

    // ---- in-block box meta (threads 0..11) ----
    if (tid < NB) {
        float4 bx = ((const float4*)boxes)[b * NB + tid];
        int lab = labels[b * NB + tid];
        bool valid = lab < NCLS;

        float bw = bx.z * (float)G, bh = bx.w * (float)G;
        int gi = min(max((int)(bx.x * (float)G), 0), G - 1);
        int gj = min(max((int)(bx.y * (float)G), 0), G - 1);

        float iou[3]; int best = 0; float bi = -1.0f;
#pragma unroll
        for (int a = 0; a < 3; a++) {
            float aw = AWc[S][a], ah = AHc[S][a];
            float inter = fminf(aw, bw) * fminf(ah, bh);
            float uni = aw * ah + 1e-16f + bw * bh - inter;
            iou[a] = inter / uni;
            if (iou[a] > bi) { bi = iou[a]; best = a; }
        }
        int flags = 0;
        if (valid) {
#pragma unroll
            for (int a = 0; a < 3; a++)
                if (iou[a] > 0.5f || a == best) flags |= (1 << a);
            flags |= (1 << (4 + best));
        }
        int cls = min(max(lab, 0), NCLS - 1);
        skey[tid] = (gj * G + gi) | (flags << 16) | (cls << 24);
        sdat[tid]      = valid ? __logf(bw / AWc[S][best] + 1e-16f) : 0.0f;
        sdat[NB + tid] = valid ? __logf(bh / AHc[S][best] + 1e-16f) : 0.0f;
    }
    __syncthreads();

    // box keys -> SGPRs (block-uniform)
    int rk[NB];
#pragma unroll
    for (int n = 0; n < NB; n++) rk[n] = __builtin_amdgcn_readfirstlane(skey[n]);

    const float* outb = outp + (size_t)b * CELLS * 8;
    float acc = 0.0f;
    const int base = chunk * (256 * ITER);

    // 4-wide explicit load staging: 8 dwordx4 in flight per wave; clamped
    // index keeps tail blocks branch-free (dup loads are in-bounds, masked out).
#pragma unroll
    for (int kb = 0; kb < ITER; kb += 4) {
        float4 Q0[4], Q1[4];
        int cs[4];
#pragma unroll
        for (int j = 0; j < 4; j++) {
            if (kb + j < ITER) {
                int c = base + (kb + j) * 256 + tid;
                cs[j] = c;
                int cc = (c < CELLS) ? c : (CELLS - 1);
                const float* cp = outb + (size_t)cc * 8;
                Q0[j] = *(const float4*)cp;
                Q1[j] = *(const float4*)(cp + 4);
            }
        }
#pragma unroll
        for (int j = 0; j < 4; j++) {
            if (kb + j < ITER) {
                float L = cell_loss<G, S>((cs[j] < CELLS) ? cs[j] : (CELLS - 1),
                                          Q0[j], Q1[j], rk, sdat);
                acc += (cs[j] < CELLS) ? L : 0.0f;
            }
        }
    }
    return acc;
}

__launch_bounds__(256)
__global__ void fused_loss(const float* __restrict__ oL,
                           const float* __restrict__ oM,
                           const float* __restrict__ oS,
                           const float* __restrict__ boxes,
                           const int* __restrict__ labels,
                           float* __restrict__ partials)
{
    __shared__ int skey[NB];
    __shared__ float sdat[2 * NB];
    __shared__ float red[256];

    const int u = blockIdx.x;
    const int tid = threadIdx.x;

    float acc;
    if (u < 128) {
        acc = scale_body<19, 0, 5>(u, 0, oL, boxes, labels, skey, sdat);
    } else if (u < 640) {
        int r = u - 128;
        acc = scale_body<38, 1, 5>(r >> 2, r & 3, oM, boxes, labels, skey, sdat);
    } else {
        int r = u - 640;
        acc = scale_body<76, 2, 8>(r / 9, r % 9, oS, boxes, labels, skey, sdat);
    }

    red[tid] = acc;
    __syncthreads();
#pragma unroll
    for (int s = 128; s > 0; s >>= 1) {
        if (tid < s) red[tid] += red[tid + s];
        __syncthreads();
    }
    if (tid == 0) partials[u] = red[0];   // plain store; kernel boundary = release
}

__global__ void final_reduce(const float* __restrict__ partials,
                             float* __restrict__ out) {
    __shared__ float red[256];
    const int tid = threadIdx.x;
    float acc = 0.0f;
#pragma unroll
    for (int i = 0; i < 7; i++) acc += partials[tid + i * 256];
    red[tid] = acc;
    __syncthreads();
#pragma unroll
    for (int s = 128; s > 0; s >>= 1) {
        if (tid < s) red[tid] += red[tid + s];
        __syncthreads();
    }
    if (tid == 0) out[0] = red[0] * (1.0f / (float)BATCH);
}

extern "C" void kernel_launch(void* const* d_in, const int* in_sizes, int n_in,
                              void* d_out, int out_size, void* d_ws, size_t ws_size,
                              hipStream_t stream) {
    const float* oL     = (const float*)d_in[0];
    const float* oM     = (const float*)d_in[1];
    const float* oS     = (const float*)d_in[2];
    const float* boxes  = (const float*)d_in[3];
    const int*   labels = (const int*)d_in[4];

    float* partials = (float*)d_ws;   // UNITS floats, fully overwritten each call

    fused_loss<<<UNITS, 256, 0, stream>>>(oL, oM, oS, boxes, labels, partials);
    final_reduce<<<1, 256, 0, stream>>>(partials, (float*)d_out);
}

// Round 9
// 24.757 us; speedup vs baseline: 3.0568x; 1.0319x over previous
//
#include <hip/hip_runtime.h>

#define NA 3
#define NCLS 3
#define NB 12
#define BATCH 128

// cells per scale (whole batch)
#define NL_CELLS (128 * 1083)    // 138624
#define NM_CELLS (128 * 4332)    // 554496
#define NS_CELLS (128 * 17328)   // 2217984
#define NTOT (NL_CELLS + NM_CELLS + NS_CELLS)  // 2911104

#define CORR_BLOCKS 384
#define STREAM_BLOCKS 1536
#define UNITS (CORR_BLOCKS + STREAM_BLOCKS)    // 1920
#define STRIDE (STREAM_BLOCKS * 256)           // 393216

// Anchors per scale (already divided by stride)
__device__ __constant__ float AWc[3][3] = {{3.625f, 4.875f, 11.65625f},
                                           {1.875f, 3.875f, 3.6875f},
                                           {1.25f,  2.0f,   4.125f}};
__device__ __constant__ float AHc[3][3] = {{2.8125f, 6.1875f, 10.1875f},
                                           {3.8125f, 2.8125f, 7.4375f},
                                           {1.625f,  3.75f,   2.875f}};

__device__ __forceinline__ float safelog(float x) {
    return fmaxf(__logf(x), -100.0f);
}

// Correction block: one (scale, image) pair per block, lanes 0..35 = (box, anchor).
// base sum counted -0.5*safelog(1-conf) for EVERY cell; here we
//   + add back 0.5*safelog(1-conf) once per unique cleared cell (noobj -> 0)
//   + add obj terms once per unique obj cell (last-box-wins, matching scatter order)
template <int G, int S>
__device__ __forceinline__ float corr_body(int b, const float* __restrict__ outp,
                                           const float* __restrict__ boxes,
                                           const int* __restrict__ labels) {
    constexpr int GG = G * G;
    constexpr int CELLS = NA * GG;
    const int l = threadIdx.x;           // 0..63 (wave 0 only)
    const int n = l / 3, a = l - n * 3;
    const bool active = (l < 36);
    const int nn = active ? n : 0;

    float4 bx = ((const float4*)boxes)[b * NB + nn];
    int lab = labels[b * NB + nn];
    bool valid = active && (lab < NCLS);

    float bw = bx.z * (float)G, bh = bx.w * (float)G;
    int gi = min(max((int)(bx.x * (float)G), 0), G - 1);
    int gj = min(max((int)(bx.y * (float)G), 0), G - 1);

    float iou[3]; int best = 0; float bi = -1.0f;
#pragma unroll
    for (int aa = 0; aa < 3; aa++) {
        float aw = AWc[S][aa], ah = AHc[S][aa];
        float inter = fminf(aw, bw) * fminf(ah, bh);
        float uni = aw * ah + 1e-16f + bw * bh - inter;
        iou[aa] = inter / uni;
        if (iou[aa] > bi) { bi = iou[aa]; best = aa; }  // first max = argmax
    }
    bool cleared = valid && (iou[a] > 0.5f || a == best);
    bool isobj   = valid && (a == best);

    unsigned key = (unsigned)(a * GG + gj * G + gi);    // cell index in (b)-slice
    unsigned v = key | (cleared ? 0x100000u : 0u) | (isobj ? 0x200000u : 0u);

    bool dupc = false, notwin = false;
#pragma unroll
    for (int j = 0; j < 36; j++) {
        unsigned vj = (unsigned)__shfl((int)v, j);
        bool same = ((vj ^ v) & 0xFFFFFu) == 0u;
        dupc   = dupc   || (same && (vj & 0x100000u) && j < l);  // earlier lane owns it
        notwin = notwin || (same && (vj & 0x200000u) && j > l);  // later box wins obj
    }

    float corr = 0.0f;
    const float* cellp = outp + ((size_t)b * CELLS + key) * 8;

    if (cleared && !dupc) {
        float conf = cellp[4];
        corr += 0.5f * safelog(1.0f - conf);   // cancel base noobj term
    }
    if (isobj && !notwin) {
        float4 q0 = *(const float4*)cellp;
        float4 q1 = *(const float4*)(cellp + 4);
        float aw = AWc[S][a], ah = AHc[S][a];
        float tw = __logf(bw / aw + 1e-16f);
        float th = __logf(bh / ah + 1e-16f);
        float px = q0.x - floorf(q0.x);
        float py = q0.y - floorf(q0.y);
        float pw = __logf(q0.z / aw + 1e-16f);
        float ph = __logf(q0.w / ah + 1e-16f);
        float dw = pw - tw, dh = ph - th;
        float conf = q1.x;
        corr += px * px + py * py + dw * dw + dh * dh;
        corr -= 5.0f * safelog(conf);                       // OBJ_SCALE * bce(conf,1)
        corr -= (lab == 0) ? safelog(q1.y) : safelog(1.0f - q1.y);
        corr -= (lab == 1) ? safelog(q1.z) : safelog(1.0f - q1.z);
        corr -= (lab == 2) ? safelog(q1.w) : safelog(1.0f - q1.w);
    }
    return corr;
}

__launch_bounds__(256)
__global__ void fused_loss(const float* __restrict__ oL,
                           const float* __restrict__ oM,
                           const float* __restrict__ oS,
                           const float* __restrict__ boxes,
                           const int* __restrict__ labels,
                           float* __restrict__ partials)
{
    __shared__ float red[256];
    const int u = blockIdx.x;
    const int tid = threadIdx.x;
    float acc = 0.0f;

    if (u < CORR_BLOCKS) {
        // corrections first in grid -> latency hides under streaming blocks
        int s = u >> 7, b = u & 127;
        if (tid < 64) {
            if      (s == 0) acc = corr_body<19, 0>(b, oL, boxes, labels);
            else if (s == 1) acc = corr_body<38, 1>(b, oM, boxes, labels);
            else             acc = corr_body<76, 2>(b, oS, boxes, labels);
        }
    } else {
        // streaming: conf-only loads, no box logic at all
        const int g0 = (u - CORR_BLOCKS) * 256 + tid;
        float cv[8];
        int ids[8];
#pragma unroll
        for (int k = 0; k < 8; k++) {
            int id = g0 + k * STRIDE;
            ids[k] = id;
            int idc = (id < NTOT) ? id : (NTOT - 1);
            const float* p; int off;
            if (idc < NL_CELLS)                { p = oL; off = idc; }
            else if (idc < NL_CELLS + NM_CELLS){ p = oM; off = idc - NL_CELLS; }
            else                               { p = oS; off = idc - NL_CELLS - NM_CELLS; }
            cv[k] = p[(size_t)off * 8 + 4];     // conf
        }
#pragma unroll
        for (int k = 0; k < 8; k++) {
            float t = -0.5f * safelog(1.0f - cv[k]);   // NOOBJ_SCALE * bce(conf,0)
            acc += (ids[k] < NTOT) ? t : 0.0f;
        }
    }

    red[tid] = acc;
    __syncthreads();
#pragma unroll
    for (int s = 128; s > 0; s >>= 1) {
        if (tid < s) red[tid] += red[tid + s];
        __syncthreads();
    }
    if (tid == 0) partials[u] = red[0];   // plain store; kernel boundary = release
}

__global__ void final_reduce(const float* __restrict__ partials,
                             float* __restrict__ out) {
    __shared__ float red[256];
    const int tid = threadIdx.x;
    float acc = 0.0f;
    for (int i = tid; i < UNITS; i += 256) acc += partials[i];
    red[tid] = acc;
    __syncthreads();
#pragma unroll
    for (int s = 128; s > 0; s >>= 1) {
        if (tid < s) red[tid] += red[tid + s];
        __syncthreads();
    }
    if (tid == 0) out[0] = red[0] * (1.0f / (float)BATCH);
}

extern "C" void kernel_launch(void* const* d_in, const int* in_sizes, int n_in,
                              void* d_out, int out_size, void* d_ws, size_t ws_size,
                              hipStream_t stream) {
    const float* oL     = (const float*)d_in[0];
    const float* oM     = (const float*)d_in[1];
    const float* oS     = (const float*)d_in[2];
    const float* boxes  = (const float*)d_in[3];
    const int*   labels = (const int*)d_in[4];

    float* partials = (float*)d_ws;   // UNITS floats, fully overwritten each call

    fused_loss<<<UNITS, 256, 0, stream>>>(oL, oM, oS, boxes, labels, partials);
    final_reduce<<<1, 256, 0, stream>>>(partials, (float*)d_out);
}

// Round 10
// 23.838 us; speedup vs baseline: 3.1746x; 1.0386x over previous
//
#include <hip/hip_runtime.h>

#define NA 3
#define NCLS 3
#define NB 12
#define BATCH 128

// float4 counts per scale (whole batch): cells * 2 (q0,q1)
#define NL_F4 277248
#define NM_F4 1108992
#define NS_F4 4435968
#define NTOT_F4 (NL_F4 + NM_F4 + NS_F4)   // 5822208
#define B1 NL_F4
#define B2 (NL_F4 + NM_F4)                 // 1386240

#define CORR_BLOCKS 384
#define SITER 16
#define STREAM_BLOCKS 1422                 // ceil(5822208 / (256*16))
#define UNITS (CORR_BLOCKS + STREAM_BLOCKS)

// Anchors per scale (already divided by stride)
__device__ __constant__ float AWc[3][3] = {{3.625f, 4.875f, 11.65625f},
                                           {1.875f, 3.875f, 3.6875f},
                                           {1.25f,  2.0f,   4.125f}};
__device__ __constant__ float AHc[3][3] = {{2.8125f, 6.1875f, 10.1875f},
                                           {3.8125f, 2.8125f, 7.4375f},
                                           {1.625f,  3.75f,   2.875f}};

__device__ __forceinline__ float safelog(float x) {
    return fmaxf(__logf(x), -100.0f);
}

// Correction block: one (scale, image) per block, lanes 0..35 = (box, anchor).
// Base sum counts -0.5*safelog(1-conf) for EVERY cell; corrections:
//   + 0.5*safelog(1-conf) once per unique cleared cell (noobj -> 0)
//   + obj terms once per unique obj cell (last-box-wins = scatter order)
template <int G, int S>
__device__ __forceinline__ float corr_body(int b, const float* __restrict__ outp,
                                           const float* __restrict__ boxes,
                                           const int* __restrict__ labels) {
    constexpr int GG = G * G;
    constexpr int CELLS = NA * GG;
    const int l = threadIdx.x;           // 0..63 (wave 0 only)
    const int n = l / 3, a = l - n * 3;
    const bool active = (l < 36);
    const int nn = active ? n : 0;

    float4 bx = ((const float4*)boxes)[b * NB + nn];
    int lab = labels[b * NB + nn];
    bool valid = active && (lab < NCLS);

    float bw = bx.z * (float)G, bh = bx.w * (float)G;
    int gi = min(max((int)(bx.x * (float)G), 0), G - 1);
    int gj = min(max((int)(bx.y * (float)G), 0), G - 1);

    float iou[3]; int best = 0; float bi = -1.0f;
#pragma unroll
    for (int aa = 0; aa < 3; aa++) {
        float aw = AWc[S][aa], ah = AHc[S][aa];
        float inter = fminf(aw, bw) * fminf(ah, bh);
        float uni = aw * ah + 1e-16f + bw * bh - inter;
        iou[aa] = inter / uni;
        if (iou[aa] > bi) { bi = iou[aa]; best = aa; }  // first max = argmax
    }
    bool cleared = valid && (iou[a] > 0.5f || a == best);
    bool isobj   = valid && (a == best);

    unsigned key = (unsigned)(a * GG + gj * G + gi);    // cell index in b-slice
    unsigned v = key | (cleared ? 0x100000u : 0u) | (isobj ? 0x200000u : 0u);

    bool dupc = false, notwin = false;
#pragma unroll
    for (int j = 0; j < 36; j++) {
        unsigned vj = (unsigned)__shfl((int)v, j);
        bool same = ((vj ^ v) & 0xFFFFFu) == 0u;
        dupc   = dupc   || (same && (vj & 0x100000u) && j < l);  // earlier lane owns it
        notwin = notwin || (same && (vj & 0x200000u) && j > l);  // later box wins obj
    }

    float corr = 0.0f;
    const float* cellp = outp + ((size_t)b * CELLS + key) * 8;

    if (cleared && !dupc) {
        float conf = cellp[4];
        corr += 0.5f * safelog(1.0f - conf);   // cancel base noobj term
    }
    if (isobj && !notwin) {
        float4 q0 = *(const float4*)cellp;
        float4 q1 = *(const float4*)(cellp + 4);
        float aw = AWc[S][a], ah = AHc[S][a];
        float tw = __logf(bw / aw + 1e-16f);
        float th = __logf(bh / ah + 1e-16f);
        float px = q0.x - floorf(q0.x);
        float py = q0.y - floorf(q0.y);
        float pw = __logf(q0.z / aw + 1e-16f);
        float ph = __logf(q0.w / ah + 1e-16f);
        float dw = pw - tw, dh = ph - th;
        float conf = q1.x;
        corr += px * px + py * py + dw * dw + dh * dh;
        corr -= 5.0f * safelog(conf);                       // OBJ_SCALE * bce(conf,1)
        corr -= (lab == 0) ? safelog(q1.y) : safelog(1.0f - q1.y);
        corr -= (lab == 1) ? safelog(q1.z) : safelog(1.0f - q1.z);
        corr -= (lab == 2) ? safelog(q1.w) : safelog(1.0f - q1.w);
    }
    return corr;
}

__launch_bounds__(256)
__global__ void fused_loss(const float* __restrict__ oL,
                           const float* __restrict__ oM,
                           const float* __restrict__ oS,
                           const float* __restrict__ boxes,
                           const int* __restrict__ labels,
                           float* __restrict__ partials)
{
    __shared__ float red[256];
    const int u = blockIdx.x;
    const int tid = threadIdx.x;
    float acc = 0.0f;

    if (u < CORR_BLOCKS) {
        // scattered, latency-bound; overlaps the streaming blocks
        int s = u >> 7, b = u & 127;
        if (tid < 64) {
            if      (s == 0) acc = corr_body<19, 0>(b, oL, boxes, labels);
            else if (s == 1) acc = corr_body<38, 1>(b, oM, boxes, labels);
            else             acc = corr_body<76, 2>(b, oS, boxes, labels);
        }
    } else {
        // streaming: flat float4 view, fully contiguous 64KB slab per block.
        // odd float4s are [conf,c0,c1,c2] -> noobj term from v.x; even -> 0.
        const float4* L4 = (const float4*)oL;
        const float4* M4 = (const float4*)oM;
        const float4* S4 = (const float4*)oS;
        const int base = (u - CORR_BLOCKS) * (256 * SITER) + tid;
        const bool odd = (tid & 1);

        float4 v[SITER];
#pragma unroll
        for (int k = 0; k < SITER; k++) {
            int idx = base + k * 256;
            int idc = (idx < NTOT_F4) ? idx : (NTOT_F4 - 1);
            const float4* p; int off;
            if (idc < B1)      { p = L4; off = idc; }
            else if (idc < B2) { p = M4; off = idc - B1; }
            else               { p = S4; off = idc - B2; }
            v[k] = p[off];
        }
#pragma unroll
        for (int k = 0; k < SITER; k++) {
            float t = -0.5f * safelog(1.0f - v[k].x);   // NOOBJ_SCALE*bce(conf,0)
            bool use = odd && ((base + k * 256) < NTOT_F4);
            acc += use ? t : 0.0f;
        }
    }

    red[tid] = acc;
    __syncthreads();
#pragma unroll
    for (int s = 128; s > 0; s >>= 1) {
        if (tid < s) red[tid] += red[tid + s];
        __syncthreads();
    }
    if (tid == 0) partials[u] = red[0];   // plain store; kernel boundary = release
}

__global__ void final_reduce(const float* __restrict__ partials,
                             float* __restrict__ out) {
    __shared__ float red[256];
    const int tid = threadIdx.x;
    float acc = 0.0f;
    for (int i = tid; i < UNITS; i += 256) acc += partials[i];
    red[tid] = acc;
    __syncthreads();
#pragma unroll
    for (int s = 128; s > 0; s >>= 1) {
        if (tid < s) red[tid] += red[tid + s];
        __syncthreads();
    }
    if (tid == 0) out[0] = red[0] * (1.0f / (float)BATCH);
}

extern "C" void kernel_launch(void* const* d_in, const int* in_sizes, int n_in,
                              void* d_out, int out_size, void* d_ws, size_t ws_size,
                              hipStream_t stream) {
    const float* oL     = (const float*)d_in[0];
    const float* oM     = (const float*)d_in[1];
    const float* oS     = (const float*)d_in[2];
    const float* boxes  = (const float*)d_in[3];
    const int*   labels = (const int*)d_in[4];

    float* partials = (float*)d_ws;   // UNITS floats, fully overwritten each call

    fused_loss<<<UNITS, 256, 0, stream>>>(oL, oM, oS, boxes, labels, partials);
    final_reduce<<<1, 256, 0, stream>>>(partials, (float*)d_out);
}

// Round 12
// 23.766 us; speedup vs baseline: 3.1843x; 1.0030x over previous
//
#include <hip/hip_runtime.h>

#define NA 3
#define NCLS 3
#define NB 12
#define BATCH 128

#define NH 2911104              // total cells across the 3 scales, whole batch
#define OL_END 138624           // cell idx < this -> oL
#define OM_END 693120           // + medium
#define B1_F4 277248            // float4 boundary L/M
#define B2_F4 1386240           // float4 boundary M/S

#define CORR_BLOCKS 384         // one (scale,image) per block, lanes 0..35 of wave 0
#define SITER 8
#define STREAM_BLOCKS 1422      // ceil(NH / (256*8))
#define UNITS (CORR_BLOCKS + STREAM_BLOCKS)   // 1806

// Anchors per scale (already divided by stride)
__device__ __constant__ float AWc[3][3] = {{3.625f, 4.875f, 11.65625f},
                                           {1.875f, 3.875f, 3.6875f},
                                           {1.25f,  2.0f,   4.125f}};
__device__ __constant__ float AHc[3][3] = {{2.8125f, 6.1875f, 10.1875f},
                                           {3.8125f, 2.8125f, 7.4375f},
                                           {1.625f,  3.75f,   2.875f}};

__device__ __forceinline__ float safelog(float x) {
    return fmaxf(__logf(x), -100.0f);
}

// Correction block: one (scale, image) per block, lanes 0..35 = (box, anchor).
// Base sum counts -0.5*safelog(1-conf) for EVERY cell; corrections:
//   + 0.5*safelog(1-conf) once per unique cleared cell (noobj -> 0)
//   + obj terms once per unique obj cell (last-box-wins = scatter order)
template <int G, int S>
__device__ __forceinline__ float corr_body(int b, const float* __restrict__ outp,
                                           const float* __restrict__ boxes,
                                           const int* __restrict__ labels) {
    constexpr int GG = G * G;
    constexpr int CELLS = NA * GG;
    const int l = threadIdx.x;           // 0..63 (wave 0 only)
    const int n = l / 3, a = l - n * 3;
    const bool active = (l < 36);
    const int nn = active ? n : 0;

    float4 bx = ((const float4*)boxes)[b * NB + nn];
    int lab = labels[b * NB + nn];
    bool valid = active && (lab < NCLS);

    float bw = bx.z * (float)G, bh = bx.w * (float)G;
    int gi = min(max((int)(bx.x * (float)G), 0), G - 1);
    int gj = min(max((int)(bx.y * (float)G), 0), G - 1);

    float iou[3]; int best = 0; float bi = -1.0f;
#pragma unroll
    for (int aa = 0; aa < 3; aa++) {
        float aw = AWc[S][aa], ah = AHc[S][aa];
        float inter = fminf(aw, bw) * fminf(ah, bh);
        float uni = aw * ah + 1e-16f + bw * bh - inter;
        iou[aa] = inter / uni;
        if (iou[aa] > bi) { bi = iou[aa]; best = aa; }  // first max = argmax
    }
    bool cleared = valid && (iou[a] > 0.5f || a == best);
    bool isobj   = valid && (a == best);

    unsigned key = (unsigned)(a * GG + gj * G + gi);    // cell index in b-slice
    unsigned v = key | (cleared ? 0x100000u : 0u) | (isobj ? 0x200000u : 0u);

    bool dupc = false, notwin = false;
#pragma unroll
    for (int j = 0; j < 36; j++) {
        unsigned vj = (unsigned)__shfl((int)v, j);      // intra-wave
        bool same = ((vj ^ v) & 0xFFFFFu) == 0u;
        dupc   = dupc   || (same && (vj & 0x100000u) && j < l);  // earlier lane owns it
        notwin = notwin || (same && (vj & 0x200000u) && j > l);  // later box wins obj
    }

    float corr = 0.0f;
    const float* cellp = outp + ((size_t)b * CELLS + key) * 8;

    if (cleared && !dupc) {
        float conf = cellp[4];
        corr += 0.5f * safelog(1.0f - conf);   // cancel base noobj term
    }
    if (isobj && !notwin) {
        float4 q0 = *(const float4*)cellp;
        float4 q1 = *(const float4*)(cellp + 4);
        float aw = AWc[S][a], ah = AHc[S][a];
        float tw = __logf(bw / aw + 1e-16f);
        float th = __logf(bh / ah + 1e-16f);
        float px = q0.x - floorf(q0.x);
        float py = q0.y - floorf(q0.y);
        float pw = __logf(q0.z / aw + 1e-16f);
        float ph = __logf(q0.w / ah + 1e-16f);
        float dw = pw - tw, dh = ph - th;
        float conf = q1.x;
        corr += px * px + py * py + dw * dw + dh * dh;
        corr -= 5.0f * safelog(conf);                       // OBJ_SCALE * bce(conf,1)
        corr -= (lab == 0) ? safelog(q1.y) : safelog(1.0f - q1.y);
        corr -= (lab == 1) ? safelog(q1.z) : safelog(1.0f - q1.z);
        corr -= (lab == 2) ? safelog(q1.w) : safelog(1.0f - q1.w);
    }
    return corr;
}

__launch_bounds__(256)
__global__ void fused_loss(const float* __restrict__ oL,
                           const float* __restrict__ oM,
                           const float* __restrict__ oS,
                           const float* __restrict__ boxes,
                           const int* __restrict__ labels,
                           float* __restrict__ partials)
{
    __shared__ float red4[4];
    const int u = blockIdx.x;
    const int tid = threadIdx.x;
    const int w = tid >> 6;
    const int l = tid & 63;
    float acc = 0.0f;

    if (u < CORR_BLOCKS) {
        // scattered, latency-bound; overlaps the streaming blocks
        int s = u >> 7, b = u & 127;
        if (tid < 64) {
            if      (s == 0) acc = corr_body<19, 0>(b, oL, boxes, labels);
            else if (s == 1) acc = corr_body<38, 1>(b, oM, boxes, labels);
            else             acc = corr_body<76, 2>(b, oS, boxes, labels);
        }
    } else {
        // streaming: conf dword only (4B of each 32B cell; all lines touched anyway)
        const int base = (u - CORR_BLOCKS) * (256 * SITER) + tid;
        float cv[SITER];
        int os[SITER];
#pragma unroll
        for (int k = 0; k < SITER; k++) {
            int o = base + k * 256;
            os[k] = o;
            int oc = (o < NH) ? o : (NH - 1);
            int f = 2 * oc + 1;                 // odd f4 = [conf, c0, c1, c2]
            const float* p; int off;
            if (oc < OL_END)      { p = oL; off = f; }
            else if (oc < OM_END) { p = oM; off = f - B1_F4; }
            else                  { p = oS; off = f - B2_F4; }
            cv[k] = p[(size_t)off * 4];         // conf
        }
#pragma unroll
        for (int k = 0; k < SITER; k++) {
            float t = -0.5f * safelog(1.0f - cv[k]);   // NOOBJ_SCALE*bce(conf,0)
            acc += (os[k] < NH) ? t : 0.0f;
        }
    }

    // wave butterfly (no barrier), then one LDS step + one per-block store
#pragma unroll
    for (int d = 1; d < 64; d <<= 1)
        acc += __shfl_xor(acc, d);
    if (l == 0) red4[w] = acc;
    __syncthreads();
    if (tid == 0)
        partials[u] = (red4[0] + red4[1]) + (red4[2] + red4[3]);
}

__global__ void final_reduce(const float* __restrict__ partials,
                             float* __restrict__ out) {
    __shared__ float red[256];
    const int tid = threadIdx.x;
    float acc = 0.0f;
    for (int i = tid; i < UNITS; i += 256) acc += partials[i];   // fixed order
    red[tid] = acc;
    __syncthreads();
#pragma unroll
    for (int s = 128; s > 0; s >>= 1) {
        if (tid < s) red[tid] += red[tid + s];
        __syncthreads();
    }
    if (tid == 0) out[0] = red[0] * (1.0f / (float)BATCH);
}

extern "C" void kernel_launch(void* const* d_in, const int* in_sizes, int n_in,
                              void* d_out, int out_size, void* d_ws, size_t ws_size,
                              hipStream_t stream) {
    const float* oL     = (const float*)d_in[0];
    const float* oM     = (const float*)d_in[1];
    const float* oS     = (const float*)d_in[2];
    const float* boxes  = (const float*)d_in[3];
    const int*   labels = (const int*)d_in[4];

    float* partials = (float*)d_ws;   // UNITS floats, fully overwritten each call

    fused_loss<<<UNITS, 256, 0, stream>>>(oL, oM, oS, boxes, labels, partials);
    final_reduce<<<1, 256, 0, stream>>>(partials, (float*)d_out);
}

// Round 13
// 22.181 us; speedup vs baseline: 3.4119x; 1.0715x over previous
//
#include <hip/hip_runtime.h>

#define NA 3
#define NCLS 3
#define NB 12
#define BATCH 128

#define NH 2911104              // total cells across the 3 scales, whole batch
#define OL_END 138624           // cell idx < this -> oL
#define OM_END 693120           // + medium
#define B1_F4 277248            // float4 boundary L/M
#define B2_F4 1386240           // float4 boundary M/S

#define CORR_BLOCKS 96          // 4 (scale,image) pairs per block, one per WAVE
#define SITER 16
#define STREAM_BLOCKS 711       // ceil(NH / (256*16))
#define UNITS (CORR_BLOCKS + STREAM_BLOCKS)   // 807

// Anchors per scale (already divided by stride)
__device__ __constant__ float AWc[3][3] = {{3.625f, 4.875f, 11.65625f},
                                           {1.875f, 3.875f, 3.6875f},
                                           {1.25f,  2.0f,   4.125f}};
__device__ __constant__ float AHc[3][3] = {{2.8125f, 6.1875f, 10.1875f},
                                           {3.8125f, 2.8125f, 7.4375f},
                                           {1.625f,  3.75f,   2.875f}};

__device__ __forceinline__ float safelog(float x) {
    return fmaxf(__logf(x), -100.0f);
}

// Correction wave: one (scale, image) per wave, lanes 0..35 = (box, anchor).
// Base sum counts -0.5*safelog(1-conf) for EVERY cell; corrections:
//   + 0.5*safelog(1-conf) once per unique cleared cell (noobj -> 0)
//   + obj terms once per unique obj cell (last-box-wins = scatter order)
template <int G, int S>
__device__ __forceinline__ float corr_body(int b, int l,
                                           const float* __restrict__ outp,
                                           const float* __restrict__ boxes,
                                           const int* __restrict__ labels) {
    constexpr int GG = G * G;
    constexpr int CELLS = NA * GG;
    const int n = l / 3, a = l - n * 3;
    const bool active = (l < 36);
    const int nn = active ? n : 0;

    float4 bx = ((const float4*)boxes)[b * NB + nn];
    int lab = labels[b * NB + nn];
    bool valid = active && (lab < NCLS);

    float bw = bx.z * (float)G, bh = bx.w * (float)G;
    int gi = min(max((int)(bx.x * (float)G), 0), G - 1);
    int gj = min(max((int)(bx.y * (float)G), 0), G - 1);

    float iou[3]; int best = 0; float bi = -1.0f;
#pragma unroll
    for (int aa = 0; aa < 3; aa++) {
        float aw = AWc[S][aa], ah = AHc[S][aa];
        float inter = fminf(aw, bw) * fminf(ah, bh);
        float uni = aw * ah + 1e-16f + bw * bh - inter;
        iou[aa] = inter / uni;
        if (iou[aa] > bi) { bi = iou[aa]; best = aa; }  // first max = argmax
    }
    bool cleared = valid && (iou[a] > 0.5f || a == best);
    bool isobj   = valid && (a == best);

    unsigned key = (unsigned)(a * GG + gj * G + gi);    // cell index in b-slice
    unsigned v = key | (cleared ? 0x100000u : 0u) | (isobj ? 0x200000u : 0u);

    bool dupc = false, notwin = false;
#pragma unroll
    for (int j = 0; j < 36; j++) {
        unsigned vj = (unsigned)__shfl((int)v, j);      // intra-wave
        bool same = ((vj ^ v) & 0xFFFFFu) == 0u;
        dupc   = dupc   || (same && (vj & 0x100000u) && j < l);  // earlier lane owns it
        notwin = notwin || (same && (vj & 0x200000u) && j > l);  // later box wins obj
    }

    float corr = 0.0f;
    const float* cellp = outp + ((size_t)b * CELLS + key) * 8;

    if (cleared && !dupc) {
        float conf = cellp[4];
        corr += 0.5f * safelog(1.0f - conf);   // cancel base noobj term
    }
    if (isobj && !notwin) {
        float4 q0 = *(const float4*)cellp;
        float4 q1 = *(const float4*)(cellp + 4);
        float aw = AWc[S][a], ah = AHc[S][a];
        float tw = __logf(bw / aw + 1e-16f);
        float th = __logf(bh / ah + 1e-16f);
        float px = q0.x - floorf(q0.x);
        float py = q0.y - floorf(q0.y);
        float pw = __logf(q0.z / aw + 1e-16f);
        float ph = __logf(q0.w / ah + 1e-16f);
        float dw = pw - tw, dh = ph - th;
        float conf = q1.x;
        corr += px * px + py * py + dw * dw + dh * dh;
        corr -= 5.0f * safelog(conf);                       // OBJ_SCALE * bce(conf,1)
        corr -= (lab == 0) ? safelog(q1.y) : safelog(1.0f - q1.y);
        corr -= (lab == 1) ? safelog(q1.z) : safelog(1.0f - q1.z);
        corr -= (lab == 2) ? safelog(q1.w) : safelog(1.0f - q1.w);
    }
    return corr;
}

__launch_bounds__(256)
__global__ void fused_loss(const float* __restrict__ oL,
                           const float* __restrict__ oM,
                           const float* __restrict__ oS,
                           const float* __restrict__ boxes,
                           const int* __restrict__ labels,
                           float* __restrict__ partials)
{
    __shared__ float red4[4];
    const int u = blockIdx.x;
    const int tid = threadIdx.x;
    const int w = tid >> 6;
    const int l = tid & 63;
    float acc = 0.0f;

    if (u < CORR_BLOCKS) {
        // one (scale,image) per wave; scattered/latency-bound, overlaps streaming
        int p = u * 4 + w;           // 0..383
        int s = p >> 7, b = p & 127;
        if      (s == 0) acc = corr_body<19, 0>(b, l, oL, boxes, labels);
        else if (s == 1) acc = corr_body<38, 1>(b, l, oM, boxes, labels);
        else             acc = corr_body<76, 2>(b, l, oS, boxes, labels);
    } else {
        // streaming: conf dword only (4B of each 32B cell; every line touched anyway)
        // 16 independent loads in flight per thread; bounds recomputed (no os[] regs)
        const int base = (u - CORR_BLOCKS) * (256 * SITER) + tid;
        float cv[SITER];
#pragma unroll
        for (int k = 0; k < SITER; k++) {
            int o = base + k * 256;
            int oc = (o < NH) ? o : (NH - 1);
            int f = 2 * oc + 1;                 // odd f4 = [conf, c0, c1, c2]
            const float* p; int off;
            if (oc < OL_END)      { p = oL; off = f; }
            else if (oc < OM_END) { p = oM; off = f - B1_F4; }
            else                  { p = oS; off = f - B2_F4; }
            cv[k] = p[(size_t)off * 4];         // conf
        }
#pragma unroll
        for (int k = 0; k < SITER; k++) {
            float t = -0.5f * safelog(1.0f - cv[k]);   // NOOBJ_SCALE*bce(conf,0)
            acc += ((base + k * 256) < NH) ? t : 0.0f;
        }
    }

    // wave butterfly (no barrier), then one LDS step + one per-block store
#pragma unroll
    for (int d = 1; d < 64; d <<= 1)
        acc += __shfl_xor(acc, d);
    if (l == 0) red4[w] = acc;
    __syncthreads();
    if (tid == 0)
        partials[u] = (red4[0] + red4[1]) + (red4[2] + red4[3]);
}

__global__ void final_reduce(const float* __restrict__ partials,
                             float* __restrict__ out) {
    __shared__ float red[256];
    const int tid = threadIdx.x;
    float acc = 0.0f;
    for (int i = tid; i < UNITS; i += 256) acc += partials[i];   // fixed order
    red[tid] = acc;
    __syncthreads();
#pragma unroll
    for (int s = 128; s > 0; s >>= 1) {
        if (tid < s) red[tid] += red[tid + s];
        __syncthreads();
    }
    if (tid == 0) out[0] = red[0] * (1.0f / (float)BATCH);
}

extern "C" void kernel_launch(void* const* d_in, const int* in_sizes, int n_in,
                              void* d_out, int out_size, void* d_ws, size_t ws_size,
                              hipStream_t stream) {
    const float* oL     = (const float*)d_in[0];
    const float* oM     = (const float*)d_in[1];
    const float* oS     = (const float*)d_in[2];
    const float* boxes  = (const float*)d_in[3];
    const int*   labels = (const int*)d_in[4];

    float* partials = (float*)d_ws;   // UNITS floats, fully overwritten each call

    fused_loss<<<UNITS, 256, 0, stream>>>(oL, oM, oS, boxes, labels, partials);
    final_reduce<<<1, 256, 0, stream>>>(partials, (float*)d_out);
}